// Round 6
// baseline (208.916 us; speedup 1.0000x reference)
//
#include <hip/hip_runtime.h>
#include <math.h>

// DynamicHybridRouter via bf16-split MFMA (3-term: xh*wh + xh*wl + xl*wh).
// R12: R6 structure is the confirmed local optimum (206.8/207.7 vs 212-218
// for all four structural rewrites R7-R10). One lever remains untried in
// isolation: R6's per-chunk `xc = xn` register copy forces a vmcnt(0)-class
// wait on ALL 8 x loads of chunk c+1 every chunk (~900cyc HBM latency
// exposed x 16 chunks ~= 6us/block on the critical path). R8/R9 attacked
// this confounded with gl_lds + sched-pins (both regressions). R12 is the
// MINIMAL fix: R6 byte-for-byte (breg staging, ds_write commit, plain
// __syncthreads, zero inline asm) + chunk loop unrolled x2 with alternating
// x buffers (xA/xB) so the copy disappears. Chunk-end wait is then only the
// compiler-emitted vmcnt(8) B-drain (B loads are issue-older than x); the
// x(c+1) wait migrates to its first use -- cvt at the top of chunk c+1's
// compute, a full chunk period (~4000cyc) after issue instead of ~900cyc.
// Numerics bit-identical to R6 -> absmax stays 0.00390625.

#define NROWS 16384
#define DIM   2048
#define NEXP  64
#define BM    64
#define TPB   256
#define CH    4                  // K-steps per chunk (k-span 128)
#define NCH   (DIM / 32 / CH)    // 16 chunks

typedef __attribute__((ext_vector_type(4))) float f32x4;
typedef __attribute__((ext_vector_type(8))) short bf16x8;

// ---- prologue: w [64][2048] f32 -> B-frag-ordered bf16 hi/lo in ws ----
// frag slot = (kstep*4 + t), kstep 0..63, t 0..3: 64 lanes x bf16x8.
// lane's frag: w[e=16t+(lane&15)][k = kstep*32 + (lane>>4)*8 + j], j=0..7.
__global__ void wfrag_kernel(const float* __restrict__ gw,
                             unsigned short* __restrict__ wsH,
                             unsigned short* __restrict__ wsL) {
  int slot  = blockIdx.x * 64 + threadIdx.x;    // 0..16383 (256 blocks x 64)
  int lane  = slot & 63;
  int t     = (slot >> 6) & 3;
  int kstep = slot >> 8;
  int e  = 16 * t + (lane & 15);
  int k0 = kstep * 32 + (lane >> 4) * 8;
  const float* src = gw + (size_t)e * DIM + k0;
  bf16x8 vh, vl;
#pragma unroll
  for (int j = 0; j < 8; ++j) {
    float w = src[j];
    unsigned u = __float_as_uint(w);
    vh[j] = (short)(u >> 16);
    float hi = __uint_as_float(u & 0xffff0000u);
    float rl = w - hi;
    vl[j] = (short)(__float_as_uint(rl) >> 16);
  }
  ((bf16x8*)wsH)[slot] = vh;
  ((bf16x8*)wsL)[slot] = vl;
}

// ---- main kernel ----
__global__ __launch_bounds__(TPB, 1)
void router_mfma(const float* __restrict__ x,
                 const unsigned short* __restrict__ wsH,
                 const unsigned short* __restrict__ wsL,
                 const float* __restrict__ gb,
                 const int* __restrict__ mat,
                 float* __restrict__ out) {
  // staging: 2 buffers x CH steps x 8 frag-blocks(4 tiles x hi/lo) x 1KB = 64KB
  // reused post-loop as the 64x64 logit slab (16KB).
  __shared__ __align__(16) char lds[2 * CH * 8 * 1024];
  __shared__ float p_a[BM], p_b[BM];
  __shared__ int   p_i[BM], p_j[BM];
  __shared__ int   s_flag;

  const int tid  = threadIdx.x;
  const int wave = tid >> 6;     // row group: rows 16*wave .. +15
  const int lane = tid & 63;
  const int m    = lane & 15;
  const int kg   = lane >> 4;
  const int row0 = blockIdx.x * BM;

  if (tid < 64) {
    unsigned long long b = __ballot(mat[lane] == 0);
    if (lane == 0) s_flag = (b != 0ull) ? 1 : 0;
  }

  f32x4 acc[4];
#pragma unroll
  for (int t = 0; t < 4; ++t) acc[t] = (f32x4)0.0f;

  const bf16x8* wsHf = (const bf16x8*)wsH;
  const bf16x8* wsLf = (const bf16x8*)wsL;

  // wave w stages step st=w of each chunk: 8 units (4 tiles x hi/lo), 1KB each.
  // src slot for chunk c, tile t: (c*CH + wave)*4 + t.
  bf16x8 breg[8];
  const float* xb = x + (size_t)(row0 + 16 * wave + m) * DIM + kg * 8;

  float4 xA[CH][2], xB[CH][2];

  // ---- prologue: stage chunk 0, prefetch x chunk 0 into xA ----
#pragma unroll
  for (int u = 0; u < 8; ++u) {
    int t = u >> 1;
    size_t slot = (size_t)((0 * CH + wave) * 4 + t);
    breg[u] = (u & 1) ? wsLf[slot * 64 + lane] : wsHf[slot * 64 + lane];
  }
#pragma unroll
  for (int st = 0; st < CH; ++st) {
    xA[st][0] = *(const float4*)(xb + st * 32);
    xA[st][1] = *(const float4*)(xb + st * 32 + 4);
  }
#pragma unroll
  for (int u = 0; u < 8; ++u)
    *(bf16x8*)(lds + (wave * 8 + u) * 1024 + lane * 16) = breg[u];
  __syncthreads();

  // chunk body: compute chunk c from cur; prefetch B(c+1) via breg/ds_write
  // and x(c+1) into nxt. No cur<-nxt copy: the x(c+1) wait happens at the
  // cvt in the NEXT chunk's compute (one full chunk period after issue).
  auto body = [&](int c, float4 (&cur)[CH][2], float4 (&nxt)[CH][2]) {
    const int par = (c & 1) * 32768;
    const bool more = (c + 1 < NCH);
    // 1) B-stage loads for chunk c+1 (oldest outstanding)
    if (more) {
#pragma unroll
      for (int u = 0; u < 8; ++u) {
        int t = u >> 1;
        size_t slot = (size_t)(((c + 1) * CH + wave) * 4 + t);
        breg[u] = (u & 1) ? wsLf[slot * 64 + lane] : wsHf[slot * 64 + lane];
      }
      // 2) x prefetch for chunk c+1 (younger than B-stage loads)
      const float* xp = xb + (c + 1) * (CH * 32);
#pragma unroll
      for (int st = 0; st < CH; ++st) {
        nxt[st][0] = *(const float4*)(xp + st * 32);
        nxt[st][1] = *(const float4*)(xp + st * 32 + 4);
      }
    }
    // 3) compute chunk c from buf[par] + cur (waits cur's loads at first cvt)
#pragma unroll
    for (int st = 0; st < CH; ++st) {
      bf16x8 bh[4], bl[4];
#pragma unroll
      for (int t = 0; t < 4; ++t) {
        bh[t] = *(const bf16x8*)(lds + par + (st * 8 + 2 * t) * 1024 + lane * 16);
        bl[t] = *(const bf16x8*)(lds + par + (st * 8 + 2 * t + 1) * 1024 + lane * 16);
      }
      bf16x8 ah, al;
#pragma unroll
      for (int q = 0; q < 2; ++q) {
        float4 v = cur[st][q];
        float ff[4] = {v.x, v.y, v.z, v.w};
#pragma unroll
        for (int j = 0; j < 4; ++j) {
          unsigned u = __float_as_uint(ff[j]);
          ah[q * 4 + j] = (short)(u >> 16);
          float hi = __uint_as_float(u & 0xffff0000u);
          float rl = ff[j] - hi;
          al[q * 4 + j] = (short)(__float_as_uint(rl) >> 16);
        }
      }
#pragma unroll
      for (int t = 0; t < 4; ++t) {
        acc[t] = __builtin_amdgcn_mfma_f32_16x16x32_bf16(ah, bh[t], acc[t], 0, 0, 0);
        acc[t] = __builtin_amdgcn_mfma_f32_16x16x32_bf16(ah, bl[t], acc[t], 0, 0, 0);
        acc[t] = __builtin_amdgcn_mfma_f32_16x16x32_bf16(al, bh[t], acc[t], 0, 0, 0);
      }
    }
    // 4) commit staged B(c+1): vmcnt wait covers only the B loads (x younger)
    if (more) {
      const int par2 = ((c + 1) & 1) * 32768;
#pragma unroll
      for (int u = 0; u < 8; ++u)
        *(bf16x8*)(lds + par2 + (wave * 8 + u) * 1024 + lane * 16) = breg[u];
    }
    // 5) one barrier per chunk
    __syncthreads();
  };

#pragma unroll 1
  for (int c = 0; c < NCH; c += 2) {
    body(c, xA, xB);
    body(c + 1, xB, xA);
  }

  // ---- epilogue: slab reuse (all compute done after final barrier) ----
  // C/D layout: col(lane&15)=expert-in-tile, row=kg*4+reg -> local x-row.
  float* slab = (float*)lds;   // [64 rows][64 experts]
  {
    float gbv[4];
#pragma unroll
    for (int t = 0; t < 4; ++t) gbv[t] = gb[16 * t + m];
#pragma unroll
    for (int t = 0; t < 4; ++t)
#pragma unroll
      for (int reg = 0; reg < 4; ++reg)
        slab[(16 * wave + kg * 4 + reg) * NEXP + 16 * t + m] = acc[t][reg] + gbv[t];
  }
  __syncthreads();

  const int flag = s_flag;

  // per-row routing (threads 0..63; rotated scan spreads LDS banks)
  if (tid < BM) {
    const float* rowp = slab + tid * NEXP;
    if (flag == 0) {
      float m1 = -1e30f, m2 = -1e30f;
      int i1 = 0, i2 = 0;
      for (int ee = 0; ee < NEXP; ++ee) {
        int e = (ee + tid) & (NEXP - 1);
        float v = rowp[e];
        if (v > m1) { m2 = m1; i2 = i1; m1 = v; i1 = e; }
        else if (v > m2) { m2 = v; i2 = e; }
      }
      float t = expf(m2 - m1);
      float pa = 1.0f / (1.0f + t);
      p_a[tid] = pa;
      p_b[tid] = t * pa;
      p_i[tid] = i1;
      p_j[tid] = i2;
    } else {
      float mx = -1e30f;
      for (int ee = 0; ee < NEXP; ++ee)
        mx = fmaxf(mx, rowp[(ee + tid) & (NEXP - 1)]);
      float ssum = 0.0f;
      for (int ee = 0; ee < NEXP; ++ee)
        ssum += expf((rowp[(ee + tid) & (NEXP - 1)] - mx) * 0.5f);  // /T=2
      p_a[tid] = mx;
      p_b[tid] = 1.0f / ssum;
    }
  }
  __syncthreads();

  // output: 64x64 tile = 1024 float4, 4 per thread
#pragma unroll
  for (int i = 0; i < 4; ++i) {
    int q  = tid + i * TPB;
    int r  = q >> 4;
    int e0 = (q & 15) * 4;
    float4 v;
    if (flag == 0) {
      int i1 = p_i[r], i2 = p_j[r];
      float a = p_a[r], b = p_b[r];
      v.x = (e0 + 0 == i1) ? a : (e0 + 0 == i2) ? b : 0.0f;
      v.y = (e0 + 1 == i1) ? a : (e0 + 1 == i2) ? b : 0.0f;
      v.z = (e0 + 2 == i1) ? a : (e0 + 2 == i2) ? b : 0.0f;
      v.w = (e0 + 3 == i1) ? a : (e0 + 3 == i2) ? b : 0.0f;
    } else {
      float mx = p_a[r], inv = p_b[r];
      const float* rowp = slab + r * NEXP + e0;
      v.x = expf((rowp[0] - mx) * 0.5f) * inv;
      v.y = expf((rowp[1] - mx) * 0.5f) * inv;
      v.z = expf((rowp[2] - mx) * 0.5f) * inv;
      v.w = expf((rowp[3] - mx) * 0.5f) * inv;
    }
    *(float4*)(out + (size_t)(row0 + r) * NEXP + e0) = v;
  }
}

extern "C" void kernel_launch(void* const* d_in, const int* in_sizes, int n_in,
                              void* d_out, int out_size, void* d_ws, size_t ws_size,
                              hipStream_t stream) {
  const float* x  = (const float*)d_in[0];
  const float* gw = (const float*)d_in[1];
  const float* gb = (const float*)d_in[2];
  const int*   mt = (const int*)d_in[3];
  float* outp = (float*)d_out;
  (void)in_sizes; (void)n_in; (void)out_size; (void)ws_size;

  unsigned short* wsH = (unsigned short*)d_ws;
  unsigned short* wsL = wsH + 64 * DIM;

  wfrag_kernel<<<256, 64, 0, stream>>>(gw, wsH, wsL);
  router_mfma<<<NROWS / BM, TPB, 0, stream>>>(x, wsH, wsL, gb, mt, outp);
}

// Round 7
// 207.408 us; speedup vs baseline: 1.0073x; 1.0073x over previous
//
#include <hip/hip_runtime.h>
#include <math.h>

// DynamicHybridRouter via bf16-split MFMA (3-term: xh*wh + xh*wl + xl*wh).
// R13 (FINAL): restoration of the best-measured kernel (R11 = R6 router
// verbatim + 256x64 wfrag; 206.8/207.7us across two measurements).
// Session ledger: six structurally distinct rewrites all regressed or were
// neutral -- R7 2 blocks/CU (217.5), R8 gl_lds+counted-vmcnt heavy pins
// (212.1), R9 boundary pins (214.2), R10 barrier-free register streams
// (218.0), R12 x-copy elimination (208.9). The timed window is dominated by
// two ~78us 512MB harness poison fills at 86-87% of achievable HBM peak
// (untouchable from kernel code); the router's residual ~25us over its x-BW
// floor is the cvt+MFMA dependency chain at 1 wave/SIMD, which every
// catalog lever failed to compress. This structure is the empirical optimum.
//
// R6 design notes (kept): grid=256 (1 block/CU), BM=64, 4 waves split ROWS
// (16 each) sharing full K. B staged to LDS once per block, double-buffered
// in 4-step chunks (16 barriers) -> B traffic 128 MB and off the critical
// path. x register-prefetched one chunk ahead, issued AFTER B-stage loads so
// the ds_write vmcnt wait leaves x in flight (in-order vmcnt).

#define NROWS 16384
#define DIM   2048
#define NEXP  64
#define BM    64
#define TPB   256
#define CH    4                  // K-steps per chunk (k-span 128)
#define NCH   (DIM / 32 / CH)    // 16 chunks

typedef __attribute__((ext_vector_type(4))) float f32x4;
typedef __attribute__((ext_vector_type(8))) short bf16x8;

// ---- prologue: w [64][2048] f32 -> B-frag-ordered bf16 hi/lo in ws ----
// frag slot = (kstep*4 + t), kstep 0..63, t 0..3: 64 lanes x bf16x8.
// lane's frag: w[e=16t+(lane&15)][k = kstep*32 + (lane>>4)*8 + j], j=0..7.
__global__ void wfrag_kernel(const float* __restrict__ gw,
                             unsigned short* __restrict__ wsH,
                             unsigned short* __restrict__ wsL) {
  int slot  = blockIdx.x * 64 + threadIdx.x;    // 0..16383 (256 blocks x 64)
  int lane  = slot & 63;
  int t     = (slot >> 6) & 3;
  int kstep = slot >> 8;
  int e  = 16 * t + (lane & 15);
  int k0 = kstep * 32 + (lane >> 4) * 8;
  const float* src = gw + (size_t)e * DIM + k0;
  bf16x8 vh, vl;
#pragma unroll
  for (int j = 0; j < 8; ++j) {
    float w = src[j];
    unsigned u = __float_as_uint(w);
    vh[j] = (short)(u >> 16);
    float hi = __uint_as_float(u & 0xffff0000u);
    float rl = w - hi;
    vl[j] = (short)(__float_as_uint(rl) >> 16);
  }
  ((bf16x8*)wsH)[slot] = vh;
  ((bf16x8*)wsL)[slot] = vl;
}

// ---- main kernel ----
__global__ __launch_bounds__(TPB, 1)
void router_mfma(const float* __restrict__ x,
                 const unsigned short* __restrict__ wsH,
                 const unsigned short* __restrict__ wsL,
                 const float* __restrict__ gb,
                 const int* __restrict__ mat,
                 float* __restrict__ out) {
  // staging: 2 buffers x CH steps x 8 frag-blocks(4 tiles x hi/lo) x 1KB = 64KB
  // reused post-loop as the 64x64 logit slab (16KB).
  __shared__ __align__(16) char lds[2 * CH * 8 * 1024];
  __shared__ float p_a[BM], p_b[BM];
  __shared__ int   p_i[BM], p_j[BM];
  __shared__ int   s_flag;

  const int tid  = threadIdx.x;
  const int wave = tid >> 6;     // row group: rows 16*wave .. +15
  const int lane = tid & 63;
  const int m    = lane & 15;
  const int kg   = lane >> 4;
  const int row0 = blockIdx.x * BM;

  if (tid < 64) {
    unsigned long long b = __ballot(mat[lane] == 0);
    if (lane == 0) s_flag = (b != 0ull) ? 1 : 0;
  }

  f32x4 acc[4];
#pragma unroll
  for (int t = 0; t < 4; ++t) acc[t] = (f32x4)0.0f;

  const bf16x8* wsHf = (const bf16x8*)wsH;
  const bf16x8* wsLf = (const bf16x8*)wsL;

  // wave w stages step st=w of each chunk: 8 units (4 tiles x hi/lo), 1KB each.
  // src slot for chunk c, tile t: (c*CH + wave)*4 + t.
  bf16x8 breg[8];
  const float* xb = x + (size_t)(row0 + 16 * wave + m) * DIM + kg * 8;

  // ---- prologue: stage chunk 0, prefetch x chunk 0 ----
#pragma unroll
  for (int u = 0; u < 8; ++u) {
    int t = u >> 1;
    size_t slot = (size_t)((0 * CH + wave) * 4 + t);
    breg[u] = (u & 1) ? wsLf[slot * 64 + lane] : wsHf[slot * 64 + lane];
  }
  float4 xc[CH][2], xn[CH][2];
#pragma unroll
  for (int st = 0; st < CH; ++st) {
    xc[st][0] = *(const float4*)(xb + st * 32);
    xc[st][1] = *(const float4*)(xb + st * 32 + 4);
  }
#pragma unroll
  for (int u = 0; u < 8; ++u)
    *(bf16x8*)(lds + (wave * 8 + u) * 1024 + lane * 16) = breg[u];
  __syncthreads();

#pragma unroll 1
  for (int c = 0; c < NCH; ++c) {
    const int par = (c & 1) * 32768;
    const bool more = (c + 1 < NCH);
    // 1) B-stage loads for chunk c+1 (oldest outstanding)
    if (more) {
#pragma unroll
      for (int u = 0; u < 8; ++u) {
        int t = u >> 1;
        size_t slot = (size_t)(((c + 1) * CH + wave) * 4 + t);
        breg[u] = (u & 1) ? wsLf[slot * 64 + lane] : wsHf[slot * 64 + lane];
      }
      // 2) x prefetch for chunk c+1 (younger than B-stage loads)
      const float* xp = xb + (c + 1) * (CH * 32);
#pragma unroll
      for (int st = 0; st < CH; ++st) {
        xn[st][0] = *(const float4*)(xp + st * 32);
        xn[st][1] = *(const float4*)(xp + st * 32 + 4);
      }
    }
    // 3) compute chunk c from buf[par] + xc (no vmcnt dependence)
#pragma unroll
    for (int st = 0; st < CH; ++st) {
      bf16x8 bh[4], bl[4];
#pragma unroll
      for (int t = 0; t < 4; ++t) {
        bh[t] = *(const bf16x8*)(lds + par + (st * 8 + 2 * t) * 1024 + lane * 16);
        bl[t] = *(const bf16x8*)(lds + par + (st * 8 + 2 * t + 1) * 1024 + lane * 16);
      }
      bf16x8 ah, al;
#pragma unroll
      for (int q = 0; q < 2; ++q) {
        float4 v = xc[st][q];
        float ff[4] = {v.x, v.y, v.z, v.w};
#pragma unroll
        for (int j = 0; j < 4; ++j) {
          unsigned u = __float_as_uint(ff[j]);
          ah[q * 4 + j] = (short)(u >> 16);
          float hi = __uint_as_float(u & 0xffff0000u);
          float rl = ff[j] - hi;
          al[q * 4 + j] = (short)(__float_as_uint(rl) >> 16);
        }
      }
#pragma unroll
      for (int t = 0; t < 4; ++t) {
        acc[t] = __builtin_amdgcn_mfma_f32_16x16x32_bf16(ah, bh[t], acc[t], 0, 0, 0);
        acc[t] = __builtin_amdgcn_mfma_f32_16x16x32_bf16(ah, bl[t], acc[t], 0, 0, 0);
        acc[t] = __builtin_amdgcn_mfma_f32_16x16x32_bf16(al, bh[t], acc[t], 0, 0, 0);
      }
    }
    // 4) commit staged B(c+1): vmcnt wait covers only the B loads (x is younger)
    if (more) {
      const int par2 = ((c + 1) & 1) * 32768;
#pragma unroll
      for (int u = 0; u < 8; ++u)
        *(bf16x8*)(lds + par2 + (wave * 8 + u) * 1024 + lane * 16) = breg[u];
#pragma unroll
      for (int st = 0; st < CH; ++st) {
        xc[st][0] = xn[st][0];
        xc[st][1] = xn[st][1];
      }
    }
    // 5) one barrier per chunk
    __syncthreads();
  }

  // ---- epilogue: slab reuse (all compute done after final barrier) ----
  // C/D layout: col(lane&15)=expert-in-tile, row=kg*4+reg -> local x-row.
  float* slab = (float*)lds;   // [64 rows][64 experts]
  {
    float gbv[4];
#pragma unroll
    for (int t = 0; t < 4; ++t) gbv[t] = gb[16 * t + m];
#pragma unroll
    for (int t = 0; t < 4; ++t)
#pragma unroll
      for (int reg = 0; reg < 4; ++reg)
        slab[(16 * wave + kg * 4 + reg) * NEXP + 16 * t + m] = acc[t][reg] + gbv[t];
  }
  __syncthreads();

  const int flag = s_flag;

  // per-row routing (threads 0..63; rotated scan spreads LDS banks)
  if (tid < BM) {
    const float* rowp = slab + tid * NEXP;
    if (flag == 0) {
      float m1 = -1e30f, m2 = -1e30f;
      int i1 = 0, i2 = 0;
      for (int ee = 0; ee < NEXP; ++ee) {
        int e = (ee + tid) & (NEXP - 1);
        float v = rowp[e];
        if (v > m1) { m2 = m1; i2 = i1; m1 = v; i1 = e; }
        else if (v > m2) { m2 = v; i2 = e; }
      }
      float t = expf(m2 - m1);
      float pa = 1.0f / (1.0f + t);
      p_a[tid] = pa;
      p_b[tid] = t * pa;
      p_i[tid] = i1;
      p_j[tid] = i2;
    } else {
      float mx = -1e30f;
      for (int ee = 0; ee < NEXP; ++ee)
        mx = fmaxf(mx, rowp[(ee + tid) & (NEXP - 1)]);
      float ssum = 0.0f;
      for (int ee = 0; ee < NEXP; ++ee)
        ssum += expf((rowp[(ee + tid) & (NEXP - 1)] - mx) * 0.5f);  // /T=2
      p_a[tid] = mx;
      p_b[tid] = 1.0f / ssum;
    }
  }
  __syncthreads();

  // output: 64x64 tile = 1024 float4, 4 per thread
#pragma unroll
  for (int i = 0; i < 4; ++i) {
    int q  = tid + i * TPB;
    int r  = q >> 4;
    int e0 = (q & 15) * 4;
    float4 v;
    if (flag == 0) {
      int i1 = p_i[r], i2 = p_j[r];
      float a = p_a[r], b = p_b[r];
      v.x = (e0 + 0 == i1) ? a : (e0 + 0 == i2) ? b : 0.0f;
      v.y = (e0 + 1 == i1) ? a : (e0 + 1 == i2) ? b : 0.0f;
      v.z = (e0 + 2 == i1) ? a : (e0 + 2 == i2) ? b : 0.0f;
      v.w = (e0 + 3 == i1) ? a : (e0 + 3 == i2) ? b : 0.0f;
    } else {
      float mx = p_a[r], inv = p_b[r];
      const float* rowp = slab + r * NEXP + e0;
      v.x = expf((rowp[0] - mx) * 0.5f) * inv;
      v.y = expf((rowp[1] - mx) * 0.5f) * inv;
      v.z = expf((rowp[2] - mx) * 0.5f) * inv;
      v.w = expf((rowp[3] - mx) * 0.5f) * inv;
    }
    *(float4*)(out + (size_t)(row0 + r) * NEXP + e0) = v;
  }
}

extern "C" void kernel_launch(void* const* d_in, const int* in_sizes, int n_in,
                              void* d_out, int out_size, void* d_ws, size_t ws_size,
                              hipStream_t stream) {
  const float* x  = (const float*)d_in[0];
  const float* gw = (const float*)d_in[1];
  const float* gb = (const float*)d_in[2];
  const int*   mt = (const int*)d_in[3];
  float* outp = (float*)d_out;
  (void)in_sizes; (void)n_in; (void)out_size; (void)ws_size;

  unsigned short* wsH = (unsigned short*)d_ws;
  unsigned short* wsL = wsH + 64 * DIM;

  wfrag_kernel<<<256, 64, 0, stream>>>(gw, wsH, wsL);
  router_mfma<<<NROWS / BM, TPB, 0, stream>>>(x, wsH, wsL, gb, mt, outp);
}